// Round 12
// baseline (2527.736 us; speedup 1.0000x reference)
//
#include <hip/hip_runtime.h>

typedef __bf16 bf16x8 __attribute__((ext_vector_type(8)));
typedef float f32x4 __attribute__((ext_vector_type(4)));
typedef unsigned int u32x4 __attribute__((ext_vector_type(4)));

union UQ { uint4 q; u32x4 p; bf16x8 v; __bf16 b[8]; unsigned long long d[2]; };

__device__ __forceinline__ unsigned short f2bf(float x){
  union { float f; unsigned u; } c; c.f = x;
  return (unsigned short)((c.u + 0x7fffu + ((c.u >> 16) & 1u)) >> 16);
}

// Pack W (512x512 f32 row-major) into canonical MFMA fragment stream:
// dst[(ntile*16 + kt)*64 + lane] = 8 bf16 of W[ntile*16 + (lane&15)][kt*32 + (lane>>4)*8 + j]
__global__ void pack_kernel(const float* __restrict__ W, uint4* __restrict__ dst){
  int tid  = blockIdx.x * 512 + threadIdx.x;   // 0..32767
  int lane = tid & 63;
  int kt   = (tid >> 6) & 15;
  int ntl  = tid >> 10;
  int row  = ntl * 16 + (lane & 15);
  int k0   = kt * 32 + ((lane >> 4) << 3);
  const float* s = &W[row * 512 + k0];
  unsigned a0 = f2bf(s[0]) | ((unsigned)f2bf(s[1]) << 16);
  unsigned a1 = f2bf(s[2]) | ((unsigned)f2bf(s[3]) << 16);
  unsigned a2 = f2bf(s[4]) | ((unsigned)f2bf(s[5]) << 16);
  unsigned a3 = f2bf(s[6]) | ((unsigned)f2bf(s[7]) << 16);
  dst[tid] = (uint4){a0, a1, a2, a3};
}

// h0[b][n] = sum_o init[b][o] * Whi[n][o]; also bf16 copy for step-0 staging
__global__ void h0_kernel(const float* __restrict__ init, const float* __restrict__ Whi,
                          float* __restrict__ h0, unsigned short* __restrict__ hb0){
  int b = blockIdx.x, n = threadIdx.x;  // 256 x 512
  __shared__ float ic[512];
  ic[n] = init[b * 512 + n];
  __syncthreads();
  const float4* wr = (const float4*)&Whi[n * 512];
  float s = 0.f;
  #pragma unroll 8
  for (int o = 0; o < 128; o++){
    float4 w = wr[o];
    s += w.x * ic[4*o] + w.y * ic[4*o+1] + w.z * ic[4*o+2] + w.w * ic[4*o+3];
  }
  h0[b * 512 + n] = s;
  hb0[b * 512 + n] = f2bf(s);
}

// Recurrence "fortress" (r8 sync, rebalanced tiers): 16 WGs x 512 threads.
// Wave w owns 64 cols (4 n-tiles). W_rec tiers:
//   kt 0..7  -> registers (32 frags = 128 VGPR, asm-loaded + pinned)
//   kt 8..9  -> LDS (64 KB, wave-local)         [was 4 kts: LDS-instr bound]
//   kt 10..15-> streamed from L2 (3 batches of 2 kts, staggered)
// Tier ORDER rotated per wave parity (odd waves do LDS-weights first) to
// spread LDS-pipe vs reg-MFMA usage across waves; setprio(1) over compute.
// h: SINGLE-buffered bf16 swizzled LDS broadcast, TWO barriers/step.
__global__ __launch_bounds__(512, 1)
void rnn_kernel(const float* __restrict__ inputs, const float* __restrict__ W_in,
                const float* __restrict__ b_in, const float* __restrict__ b_rec,
                const uint4* __restrict__ wfrag, const float* __restrict__ h0,
                const unsigned short* __restrict__ hb0, float* __restrict__ hidden){
  const int m = blockIdx.x;
  const int g16 = m << 4;
  const int tid = threadIdx.x, w = tid >> 6, lane = tid & 63;
  const int col = lane & 15, quad = lane >> 4;
  const int nbase = w << 6;
  const int swc = (col & 7) << 3;

  __shared__ unsigned short hbuf[16 * 512];  // 16 KB, swizzled bf16 h
  __shared__ uint4 wlds[8][8][64];           // 64 KB, W kt 8..9 x 4 ntiles

  // ---- persistent register weights kt0..7 (asm load: cannot rematerialize)
  UQ u[32];
  #pragma unroll
  for (int kt = 0; kt < 8; kt++)
    #pragma unroll
    for (int nt = 0; nt < 4; nt++){
      const uint4* src = &wfrag[(((w << 2) + nt) * 16 + kt) * 64 + lane];
      asm volatile("global_load_dwordx4 %0, %1, off"
                   : "=v"(u[kt * 4 + nt].p) : "v"(src) : "memory");
    }
  asm volatile("s_waitcnt vmcnt(0)" ::: "memory");
  #pragma unroll
  for (int j = 0; j < 32; j++)
    asm volatile("" : "+v"(u[j].d[0]), "+v"(u[j].d[1]));

  // ---- LDS weight tier kt8..9 (wave-local region)
  #pragma unroll
  for (int kt = 8; kt < 10; kt++)
    #pragma unroll
    for (int nt = 0; nt < 4; nt++)
      wlds[w][(kt - 8) * 4 + nt][lane] = wfrag[(((w << 2) + nt) * 16 + kt) * 64 + lane];

  // ---- augmented W frag (A-operand): quad0 lanes hold (w0, w1, bias)
  UQ uaug[4];
  #pragma unroll
  for (int nt = 0; nt < 4; nt++){
    uaug[nt].d[0] = 0; uaug[nt].d[1] = 0;
    if (quad == 0){
      int n = nbase + nt * 16 + col;
      uaug[nt].b[0] = (__bf16)W_in[2 * n];
      uaug[nt].b[1] = (__bf16)W_in[2 * n + 1];
      uaug[nt].b[2] = (__bf16)(b_in[n] + b_rec[n]);
    }
  }

  // ---- h regs: lane owns batch=col, 16 cols (4 per n-tile)
  float h[16];
  #pragma unroll
  for (int nt = 0; nt < 4; nt++){
    float4 h4 = *(const float4*)&h0[(g16 + col) * 512 + nbase + nt * 16 + (quad << 2)];
    h[nt*4+0] = h4.x; h[nt*4+1] = h4.y; h[nt*4+2] = h4.z; h[nt*4+3] = h4.w;
  }

  { // hbuf from hb0 (full 16x512, swizzled)
    int b = tid >> 5, n0 = (tid & 31) << 4;
    const uint4* s4 = (const uint4*)&hb0[(g16 + b) * 512 + n0];
    uint4 v0 = s4[0], v1 = s4[1];
    int sw = (b & 7) << 3;
    *(uint4*)&hbuf[(b << 9) + (n0 ^ sw)]       = v0;
    *(uint4*)&hbuf[(b << 9) + ((n0 + 8) ^ sw)] = v1;
  }
  __syncthreads();

  unsigned long long wsp = (unsigned long long)wfrag;
  const float2* xsrc = (const float2*)&inputs[((size_t)(g16 + col)) << 10];
  const bool ldsw_first = (w & 1);

#define ISSUE(b2) { /* stream batch b2: kts 10+2*b2, 11+2*b2 */                   \
    _Pragma("unroll")                                                             \
    for (int kk_ = 0; kk_ < 2; kk_++){                                            \
      const int kt_ = 10 + 2*(b2) + kk_;                                          \
      _Pragma("unroll")                                                           \
      for (int nt_ = 0; nt_ < 4; nt_++)                                           \
        sv[(kt_-10)*4 + nt_].q = ws[(((w << 2) + nt_) * 16 + kt_) * 64 + lane];   \
    } }

#define HREAD(kt_) *(const uint4*)&hbuf[(col << 9) + ((((kt_) << 5) + (quad << 3)) ^ swc)]

#define TIER_REG {                                                                \
    _Pragma("unroll")                                                             \
    for (int kt = 0; kt < 8; kt++){                                               \
      UQ bfr; bfr.q = HREAD(kt);                                                  \
      _Pragma("unroll")                                                           \
      for (int nt = 0; nt < 4; nt++)                                              \
        acc[nt] = __builtin_amdgcn_mfma_f32_16x16x32_bf16(u[kt*4+nt].v, bfr.v, acc[nt], 0, 0, 0); \
      if (kt == 2) ISSUE(1);                                                      \
      if (kt == 5) ISSUE(2);                                                      \
    } }

#define TIER_LDSW {                                                               \
    _Pragma("unroll")                                                             \
    for (int kt = 8; kt < 10; kt++){                                              \
      UQ bfr; bfr.q = HREAD(kt);                                                  \
      _Pragma("unroll")                                                           \
      for (int nt = 0; nt < 4; nt++){                                             \
        UQ a; a.q = wlds[w][(kt - 8) * 4 + nt][lane];                             \
        acc[nt] = __builtin_amdgcn_mfma_f32_16x16x32_bf16(a.v, bfr.v, acc[nt], 0, 0, 0); \
      } } }

  for (int t = 0; t < 512; t++){
    asm volatile("" : "+s"(wsp));             // re-opaque: forbid hoisting stream loads
    const uint4* ws = (const uint4*)wsp;

    // aug B frag: (x0, x1, 1) on quad0
    UQ baug; baug.d[0] = 0; baug.d[1] = 0;
    float2 xv = xsrc[t];
    if (quad == 0){
      baug.b[0] = (__bf16)xv.x; baug.b[1] = (__bf16)xv.y; baug.b[2] = (__bf16)1.0f;
    }

    f32x4 acc[4];
    #pragma unroll
    for (int nt = 0; nt < 4; nt++)
      acc[nt] = __builtin_amdgcn_mfma_f32_16x16x32_bf16(uaug[nt].v, baug.v,
                                                        (f32x4){0.f,0.f,0.f,0.f}, 0, 0, 0);

    UQ sv[24];
    ISSUE(0);
    __builtin_amdgcn_s_setprio(1);
    if (ldsw_first){ TIER_LDSW; TIER_REG; }
    else           { TIER_REG; TIER_LDSW; }
    // kt 10..15: streamed weights
    #pragma unroll
    for (int kt = 10; kt < 16; kt++){
      UQ bfr; bfr.q = HREAD(kt);
      #pragma unroll
      for (int nt = 0; nt < 4; nt++)
        acc[nt] = __builtin_amdgcn_mfma_f32_16x16x32_bf16(sv[(kt-10)*4+nt].v, bfr.v, acc[nt], 0, 0, 0);
    }
    __builtin_amdgcn_s_setprio(0);

    __syncthreads();   // barrier A: all hbuf reads complete before any write

    // ---- epilogue: h = 0.9h + 0.1 - 0.2/(exp(2z)+1); write hbuf + hidden
    #pragma unroll
    for (int nt = 0; nt < 4; nt++){
      UQ hw; hw.d[0] = 0; hw.d[1] = 0;
      #pragma unroll
      for (int r = 0; r < 4; r++){
        float z  = acc[nt][r];
        float e  = __expf(2.0f * z);
        float rc = __builtin_amdgcn_rcpf(e + 1.0f);
        float hn = fmaf(0.9f, h[nt*4+r], 0.1f) - 0.2f * rc;
        h[nt*4+r] = hn;
        hw.b[r] = (__bf16)hn;
      }
      *(unsigned long long*)&hbuf[(col << 9) + ((nbase + (nt << 4) + (quad << 2)) ^ swc)] = hw.d[0];
      *(float4*)&hidden[((size_t)(g16 + col) * 512 + t) * 512 + nbase + (nt << 4) + (quad << 2)] =
          (float4){h[nt*4+0], h[nt*4+1], h[nt*4+2], h[nt*4+3]};
    }
    __syncthreads();   // barrier B: h_t visible before next step's reads
  }
#undef ISSUE
#undef HREAD
#undef TIER_REG
#undef TIER_LDSW
}

// outputs = hidden @ W_out^T : 1024 WGs x 8 waves; WG tile 128M x 512N.
// Full A-tile (128x512) as bf16 in LDS (128 KB, XOR-swizzled), staged ONCE
// -> ONE barrier total (was 32). W-fragments streamed per-wave from L2;
// 8-wave TLP hides W latency. 1 WG/CU.
__global__ __launch_bounds__(512, 1)
void out_gemm(const float* __restrict__ hidden, const uint4* __restrict__ wofrag,
              float* __restrict__ outp){
  const int tid  = threadIdx.x;
  const int w    = tid >> 6;
  const int lane = tid & 63;
  const int col  = lane & 15;
  const int quad = lane >> 4;
  const int ms   = w >> 1;
  const int nh   = w & 1;
  const int m0   = blockIdx.x << 7;

  __shared__ unsigned short albf[128 * 512];  // 128 KB swizzled bf16 A-tile

  // ---- stage full A-tile: 16384 float4 loads over 512 threads (32 each)
  #pragma unroll 4
  for (int i = 0; i < 32; i++){
    int idx = i * 512 + tid;            // 0..16383
    int r   = idx >> 7;                 // 0..127
    int c4  = (idx & 127) << 2;         // 0..508 step 4
    float4 v = *(const float4*)&hidden[(size_t)(m0 + r) * 512 + c4];
    unsigned lo = f2bf(v.x) | ((unsigned)f2bf(v.y) << 16);
    unsigned hi = f2bf(v.z) | ((unsigned)f2bf(v.w) << 16);
    int byteoff = (r << 10) + (((c4 << 1)) ^ ((r & 7) << 4));
    *(uint2*)((char*)albf + byteoff) = (uint2){lo, hi};
  }
  __syncthreads();

  f32x4 acc[2][16];
  #pragma unroll
  for (int mt = 0; mt < 2; mt++)
    #pragma unroll
    for (int nt = 0; nt < 16; nt++) acc[mt][nt] = (f32x4){0.f, 0.f, 0.f, 0.f};

  for (int kt = 0; kt < 16; kt++){
    bf16x8 af[2];
    #pragma unroll
    for (int mt = 0; mt < 2; mt++){
      int rl = (ms << 5) + (mt << 4) + col;
      int byteoff = (rl << 10) + (((kt << 6) + (quad << 4)) ^ ((rl & 7) << 4));
      af[mt] = *(const bf16x8*)((const char*)albf + byteoff);
    }
    #pragma unroll
    for (int nt = 0; nt < 16; nt++){
      UQ u; u.q = wofrag[((((nh << 4) + nt) << 4) + kt) * 64 + lane];
      acc[0][nt] = __builtin_amdgcn_mfma_f32_16x16x32_bf16(af[0], u.v, acc[0][nt], 0, 0, 0);
      acc[1][nt] = __builtin_amdgcn_mfma_f32_16x16x32_bf16(af[1], u.v, acc[1][nt], 0, 0, 0);
    }
  }

  #pragma unroll
  for (int mt = 0; mt < 2; mt++)
    #pragma unroll
    for (int nt = 0; nt < 16; nt++)
      #pragma unroll
      for (int r = 0; r < 4; r++)
        outp[(size_t)(m0 + (ms << 5) + (mt << 4) + (quad << 2) + r) * 512
             + (nh << 8) + (nt << 4) + col] = acc[mt][nt][r];
}

extern "C" void kernel_launch(void* const* d_in, const int* in_sizes, int n_in,
                              void* d_out, int out_size, void* d_ws, size_t ws_size,
                              hipStream_t stream){
  const float* inputs  = (const float*)d_in[0];  // (256,512,2)
  const float* initc   = (const float*)d_in[1];  // (256,512)
  const float* W_in    = (const float*)d_in[2];  // (512,2)
  const float* b_in    = (const float*)d_in[3];  // (512)
  const float* W_rec   = (const float*)d_in[4];  // (512,512)
  const float* b_rec   = (const float*)d_in[5];  // (512)
  const float* W_out   = (const float*)d_in[6];  // (512,512)
  const float* W_hi    = (const float*)d_in[7];  // (512,512)

  float* hidden  = (float*)d_out;                 // 256*512*512
  float* outputs = hidden + (size_t)67108864;     // second half

  char* ws = (char*)d_ws;
  uint4*          wrec_f = (uint4*)ws;                           // 512 KB
  uint4*          wout_f = (uint4*)(ws + (512 << 10));           // 512 KB
  float*          h0     = (float*)(ws + (1024 << 10));          // 512 KB
  unsigned short* hb0    = (unsigned short*)(ws + (1536 << 10)); // 256 KB

  pack_kernel<<<64, 512, 0, stream>>>(W_rec, wrec_f);
  pack_kernel<<<64, 512, 0, stream>>>(W_out, wout_f);
  h0_kernel<<<256, 512, 0, stream>>>(initc, W_hi, h0, hb0);
  rnn_kernel<<<16, 512, 0, stream>>>(inputs, W_in, b_in, b_rec, wrec_f, h0, hb0, hidden);
  out_gemm<<<1024, 512, 0, stream>>>(hidden, wout_f, outputs);
}

// Round 14
// 2104.703 us; speedup vs baseline: 1.2010x; 1.2010x over previous
//
#include <hip/hip_runtime.h>

typedef __bf16 bf16x8 __attribute__((ext_vector_type(8)));
typedef float f32x4 __attribute__((ext_vector_type(4)));
typedef unsigned int u32x4 __attribute__((ext_vector_type(4)));

union UQ { uint4 q; u32x4 p; bf16x8 v; __bf16 b[8]; unsigned long long d[2]; };

__device__ __forceinline__ unsigned short f2bf(float x){
  union { float f; unsigned u; } c; c.f = x;
  return (unsigned short)((c.u + 0x7fffu + ((c.u >> 16) & 1u)) >> 16);
}

// Pack W (512x512 f32 row-major) into canonical MFMA fragment stream:
// dst[(ntile*16 + kt)*64 + lane] = 8 bf16 of W[ntile*16 + (lane&15)][kt*32 + (lane>>4)*8 + j]
__global__ void pack_kernel(const float* __restrict__ W, uint4* __restrict__ dst){
  int tid  = blockIdx.x * 512 + threadIdx.x;   // 0..32767
  int lane = tid & 63;
  int kt   = (tid >> 6) & 15;
  int ntl  = tid >> 10;
  int row  = ntl * 16 + (lane & 15);
  int k0   = kt * 32 + ((lane >> 4) << 3);
  const float* s = &W[row * 512 + k0];
  unsigned a0 = f2bf(s[0]) | ((unsigned)f2bf(s[1]) << 16);
  unsigned a1 = f2bf(s[2]) | ((unsigned)f2bf(s[3]) << 16);
  unsigned a2 = f2bf(s[4]) | ((unsigned)f2bf(s[5]) << 16);
  unsigned a3 = f2bf(s[6]) | ((unsigned)f2bf(s[7]) << 16);
  dst[tid] = (uint4){a0, a1, a2, a3};
}

// h0[b][n] = sum_o init[b][o] * Whi[n][o]; also bf16 copy for step-0 staging
__global__ void h0_kernel(const float* __restrict__ init, const float* __restrict__ Whi,
                          float* __restrict__ h0, unsigned short* __restrict__ hb0){
  int b = blockIdx.x, n = threadIdx.x;  // 256 x 512
  __shared__ float ic[512];
  ic[n] = init[b * 512 + n];
  __syncthreads();
  const float4* wr = (const float4*)&Whi[n * 512];
  float s = 0.f;
  #pragma unroll 8
  for (int o = 0; o < 128; o++){
    float4 w = wr[o];
    s += w.x * ic[4*o] + w.y * ic[4*o+1] + w.z * ic[4*o+2] + w.w * ic[4*o+3];
  }
  h0[b * 512 + n] = s;
  hb0[b * 512 + n] = f2bf(s);
}

// Recurrence "fortress" (r8 sync discipline, rebalanced tiers):
// 16 WGs x 512 threads, one per CU, ZERO cross-WG traffic.
// Wave w owns 64 cols (4 n-tiles). W_rec tiers:
//   kt 0..9  -> registers (40 frags = 160 VGPR; asm-loaded in 2-kt batches
//               with vmcnt(0)+pin per batch — bounded in-flight regs, r13 fix)
//   kt 10..13-> LDS (128 KB, wave-local)
//   kt 14..15-> streamed from L2 each step (64 KB/step/CU)
// h: SINGLE-buffered bf16 swizzled LDS broadcast, TWO barriers per step.
// x-projection + biases folded into MFMA via augmented K-tile.
__global__ __launch_bounds__(512, 2)
void rnn_kernel(const float* __restrict__ inputs, const float* __restrict__ W_in,
                const float* __restrict__ b_in, const float* __restrict__ b_rec,
                const uint4* __restrict__ wfrag, const float* __restrict__ h0,
                const unsigned short* __restrict__ hb0, float* __restrict__ hidden){
  const int m = blockIdx.x;
  const int g16 = m << 4;
  const int tid = threadIdx.x, w = tid >> 6, lane = tid & 63;
  const int col = lane & 15, quad = lane >> 4;
  const int nbase = w << 6;
  const int swc = (col & 7) << 3;

  __shared__ unsigned short hbuf[16 * 512];  // 16 KB, swizzled bf16 h
  __shared__ uint4 wlds[8][16][64];          // 128 KB, W kt 10..13

  // ---- register weights kt0..9: 2-kt batches (8 loads, 32 regs in flight)
  UQ u[40];
  #pragma unroll
  for (int kb = 0; kb < 5; kb++){
    #pragma unroll
    for (int kk = 0; kk < 2; kk++)
      #pragma unroll
      for (int nt = 0; nt < 4; nt++){
        const int j = (kb * 2 + kk) * 4 + nt;
        const uint4* src = &wfrag[(((w << 2) + nt) * 16 + (kb * 2 + kk)) * 64 + lane];
        asm volatile("global_load_dwordx4 %0, %1, off"
                     : "=v"(u[j].p) : "v"(src) : "memory");
      }
    asm volatile("s_waitcnt vmcnt(0)" ::: "memory");
    #pragma unroll
    for (int kk = 0; kk < 2; kk++)
      #pragma unroll
      for (int nt = 0; nt < 4; nt++){
        const int j = (kb * 2 + kk) * 4 + nt;
        asm volatile("" : "+v"(u[j].d[0]), "+v"(u[j].d[1]));
      }
  }

  // ---- LDS weight tier kt10..13 (wave-local region)
  #pragma unroll
  for (int kt = 10; kt < 14; kt++)
    #pragma unroll
    for (int nt = 0; nt < 4; nt++)
      wlds[w][(kt - 10) * 4 + nt][lane] = wfrag[(((w << 2) + nt) * 16 + kt) * 64 + lane];

  // ---- augmented W frag (A-operand): quad0 lanes hold (w0, w1, bias)
  UQ uaug[4];
  #pragma unroll
  for (int nt = 0; nt < 4; nt++){
    uaug[nt].d[0] = 0; uaug[nt].d[1] = 0;
    if (quad == 0){
      int n = nbase + nt * 16 + col;
      uaug[nt].b[0] = (__bf16)W_in[2 * n];
      uaug[nt].b[1] = (__bf16)W_in[2 * n + 1];
      uaug[nt].b[2] = (__bf16)(b_in[n] + b_rec[n]);
    }
  }

  // ---- h regs: lane owns batch=col, 16 cols (4 per n-tile)
  float h[16];
  #pragma unroll
  for (int nt = 0; nt < 4; nt++){
    float4 h4 = *(const float4*)&h0[(g16 + col) * 512 + nbase + nt * 16 + (quad << 2)];
    h[nt*4+0] = h4.x; h[nt*4+1] = h4.y; h[nt*4+2] = h4.z; h[nt*4+3] = h4.w;
  }

  { // hbuf from hb0 (full 16x512, swizzled)
    int b = tid >> 5, n0 = (tid & 31) << 4;
    const uint4* s4 = (const uint4*)&hb0[(g16 + b) * 512 + n0];
    uint4 v0 = s4[0], v1 = s4[1];
    int sw = (b & 7) << 3;
    *(uint4*)&hbuf[(b << 9) + (n0 ^ sw)]       = v0;
    *(uint4*)&hbuf[(b << 9) + ((n0 + 8) ^ sw)] = v1;
  }
  __syncthreads();

  unsigned long long wsp = (unsigned long long)wfrag;
  const float2* xsrc = (const float2*)&inputs[((size_t)(g16 + col)) << 10];

#define ISSUE(b1) { const int kt_ = 14 + (b1);                                    \
    _Pragma("unroll")                                                             \
    for (int nt_ = 0; nt_ < 4; nt_++)                                             \
      sv[(b1)*4 + nt_].q = ws[(((w << 2) + nt_) * 16 + kt_) * 64 + lane]; }

#define HREAD(kt_) *(const uint4*)&hbuf[(col << 9) + ((((kt_) << 5) + (quad << 3)) ^ swc)]

  for (int t = 0; t < 512; t++){
    asm volatile("" : "+s"(wsp));             // re-opaque: forbid hoisting stream loads
    const uint4* ws = (const uint4*)wsp;

    // aug B frag: (x0, x1, 1) on quad0
    UQ baug; baug.d[0] = 0; baug.d[1] = 0;
    float2 xv = xsrc[t];
    if (quad == 0){
      baug.b[0] = (__bf16)xv.x; baug.b[1] = (__bf16)xv.y; baug.b[2] = (__bf16)1.0f;
    }

    f32x4 acc[4];
    #pragma unroll
    for (int nt = 0; nt < 4; nt++)
      acc[nt] = __builtin_amdgcn_mfma_f32_16x16x32_bf16(uaug[nt].v, baug.v,
                                                        (f32x4){0.f,0.f,0.f,0.f}, 0, 0, 0);

    UQ sv[8];
    ISSUE(0);
    // kt 0..9: register weights
    #pragma unroll
    for (int kt = 0; kt < 10; kt++){
      UQ bfr; bfr.q = HREAD(kt);
      #pragma unroll
      for (int nt = 0; nt < 4; nt++)
        acc[nt] = __builtin_amdgcn_mfma_f32_16x16x32_bf16(u[kt*4+nt].v, bfr.v, acc[nt], 0, 0, 0);
      if (kt == 2) ISSUE(1);
    }
    // kt 10..13: LDS weights
    #pragma unroll
    for (int kt = 10; kt < 14; kt++){
      UQ bfr; bfr.q = HREAD(kt);
      #pragma unroll
      for (int nt = 0; nt < 4; nt++){
        UQ a; a.q = wlds[w][(kt - 10) * 4 + nt][lane];
        acc[nt] = __builtin_amdgcn_mfma_f32_16x16x32_bf16(a.v, bfr.v, acc[nt], 0, 0, 0);
      }
    }
    // kt 14..15: streamed weights
    #pragma unroll
    for (int kt = 14; kt < 16; kt++){
      UQ bfr; bfr.q = HREAD(kt);
      #pragma unroll
      for (int nt = 0; nt < 4; nt++)
        acc[nt] = __builtin_amdgcn_mfma_f32_16x16x32_bf16(sv[(kt-14)*4+nt].v, bfr.v, acc[nt], 0, 0, 0);
    }

    __syncthreads();   // barrier A: ALL waves' hbuf reads complete before any write

    // ---- epilogue: h = 0.9h + 0.1 - 0.2/(exp(2z)+1); write hbuf + hidden
    #pragma unroll
    for (int nt = 0; nt < 4; nt++){
      UQ hw; hw.d[0] = 0; hw.d[1] = 0;
      #pragma unroll
      for (int r = 0; r < 4; r++){
        float z  = acc[nt][r];
        float e  = __expf(2.0f * z);
        float rc = __builtin_amdgcn_rcpf(e + 1.0f);
        float hn = fmaf(0.9f, h[nt*4+r], 0.1f) - 0.2f * rc;
        h[nt*4+r] = hn;
        hw.b[r] = (__bf16)hn;
      }
      *(unsigned long long*)&hbuf[(col << 9) + ((nbase + (nt << 4) + (quad << 2)) ^ swc)] = hw.d[0];
      *(float4*)&hidden[((size_t)(g16 + col) * 512 + t) * 512 + nbase + (nt << 4) + (quad << 2)] =
          (float4){h[nt*4+0], h[nt*4+1], h[nt*4+2], h[nt*4+3]};
    }
    __syncthreads();   // barrier B: h_t visible before next step's reads
  }
#undef ISSUE
#undef HREAD
}

// outputs = hidden @ W_out^T : 1024 WGs x 8 waves; WG tile 128M x 512N.
// W-fragments for the current kt staged into LDS once per iteration (r10-proven).
__global__ __launch_bounds__(512, 2)
void out_gemm(const float* __restrict__ hidden, const uint4* __restrict__ wofrag,
              float* __restrict__ outp){
  const int tid  = threadIdx.x;
  const int w    = tid >> 6;
  const int lane = tid & 63;
  const int col  = lane & 15;
  const int quad = lane >> 4;
  const int ms   = w >> 1;
  const int nh   = w & 1;
  const int m0   = blockIdx.x << 7;

  __shared__ unsigned short albf[128 * 32];  // 8 KB swizzled bf16 A-tile
  __shared__ uint4 wq[32][64];               // 32 KB W-frags for current kt

  f32x4 acc[2][16];
  #pragma unroll
  for (int mt = 0; mt < 2; mt++)
    #pragma unroll
    for (int nt = 0; nt < 16; nt++) acc[mt][nt] = (f32x4){0.f, 0.f, 0.f, 0.f};

  for (int kt = 0; kt < 16; kt++){
    #pragma unroll
    for (int i = 0; i < 2; i++){
      int r  = (tid >> 3) + (i << 6);
      int c4 = (tid & 7) << 2;
      float4 v = *(const float4*)&hidden[(m0 + r) * 512 + (kt << 5) + c4];
      unsigned lo = f2bf(v.x) | ((unsigned)f2bf(v.y) << 16);
      unsigned hi = f2bf(v.z) | ((unsigned)f2bf(v.w) << 16);
      int byteoff = (r << 6) + ((c4 << 1) ^ (((r >> 1) & 3) << 4));
      *(uint2*)((char*)albf + byteoff) = (uint2){lo, hi};
    }
    #pragma unroll
    for (int j = 0; j < 4; j++){
      int idx = (j << 9) + tid;            // 0..2047
      wq[idx >> 6][idx & 63] = wofrag[(((idx >> 6) << 4) + kt) * 64 + (idx & 63)];
    }
    __syncthreads();

    bf16x8 af[2];
    #pragma unroll
    for (int mt = 0; mt < 2; mt++){
      int rl = (ms << 5) + (mt << 4) + col;
      int byteoff = (rl << 6) + ((quad << 4) ^ (((rl >> 1) & 3) << 4));
      af[mt] = *(const bf16x8*)((const char*)albf + byteoff);
    }

    #pragma unroll
    for (int nt = 0; nt < 16; nt++){
      UQ u; u.q = wq[(nh << 4) + nt][lane];
      acc[0][nt] = __builtin_amdgcn_mfma_f32_16x16x32_bf16(af[0], u.v, acc[0][nt], 0, 0, 0);
      acc[1][nt] = __builtin_amdgcn_mfma_f32_16x16x32_bf16(af[1], u.v, acc[1][nt], 0, 0, 0);
    }
    __syncthreads();
  }

  #pragma unroll
  for (int mt = 0; mt < 2; mt++)
    #pragma unroll
    for (int nt = 0; nt < 16; nt++)
      #pragma unroll
      for (int r = 0; r < 4; r++)
        outp[(size_t)(m0 + (ms << 5) + (mt << 4) + (quad << 2) + r) * 512
             + (nh << 8) + (nt << 4) + col] = acc[mt][nt][r];
}

extern "C" void kernel_launch(void* const* d_in, const int* in_sizes, int n_in,
                              void* d_out, int out_size, void* d_ws, size_t ws_size,
                              hipStream_t stream){
  const float* inputs  = (const float*)d_in[0];  // (256,512,2)
  const float* initc   = (const float*)d_in[1];  // (256,512)
  const float* W_in    = (const float*)d_in[2];  // (512,2)
  const float* b_in    = (const float*)d_in[3];  // (512)
  const float* W_rec   = (const float*)d_in[4];  // (512,512)
  const float* b_rec   = (const float*)d_in[5];  // (512)
  const float* W_out   = (const float*)d_in[6];  // (512,512)
  const float* W_hi    = (const float*)d_in[7];  // (512,512)

  float* hidden  = (float*)d_out;                 // 256*512*512
  float* outputs = hidden + (size_t)67108864;     // second half

  char* ws = (char*)d_ws;
  uint4*          wrec_f = (uint4*)ws;                           // 512 KB
  uint4*          wout_f = (uint4*)(ws + (512 << 10));           // 512 KB
  float*          h0     = (float*)(ws + (1024 << 10));          // 512 KB
  unsigned short* hb0    = (unsigned short*)(ws + (1536 << 10)); // 256 KB

  pack_kernel<<<64, 512, 0, stream>>>(W_rec, wrec_f);
  pack_kernel<<<64, 512, 0, stream>>>(W_out, wout_f);
  h0_kernel<<<256, 512, 0, stream>>>(initc, W_hi, h0, hb0);
  rnn_kernel<<<16, 512, 0, stream>>>(inputs, W_in, b_in, b_rec, wrec_f, h0, hb0, hidden);
  out_gemm<<<1024, 512, 0, stream>>>(hidden, wout_f, outputs);
}

// Round 15
// 1803.878 us; speedup vs baseline: 1.4013x; 1.1668x over previous
//
#include <hip/hip_runtime.h>

typedef __bf16 bf16x8 __attribute__((ext_vector_type(8)));
typedef float f32x4 __attribute__((ext_vector_type(4)));
typedef unsigned int u32x4 __attribute__((ext_vector_type(4)));

union UQ { uint4 q; u32x4 p; bf16x8 v; __bf16 b[8]; unsigned long long d[2]; };

__device__ __forceinline__ unsigned short f2bf(float x){
  union { float f; unsigned u; } c; c.f = x;
  return (unsigned short)((c.u + 0x7fffu + ((c.u >> 16) & 1u)) >> 16);
}

__global__ void zero_flags(int* __restrict__ p){
  p[threadIdx.x] = 0;
}

// Pack W (512x512 f32 row-major) into canonical MFMA fragment stream:
// dst[(ntile*16 + kt)*64 + lane] = 8 bf16 of W[ntile*16 + (lane&15)][kt*32 + (lane>>4)*8 + j]
__global__ void pack_kernel(const float* __restrict__ W, uint4* __restrict__ dst){
  int tid  = blockIdx.x * 512 + threadIdx.x;   // 0..32767
  int lane = tid & 63;
  int kt   = (tid >> 6) & 15;
  int ntl  = tid >> 10;
  int row  = ntl * 16 + (lane & 15);
  int k0   = kt * 32 + ((lane >> 4) << 3);
  const float* s = &W[row * 512 + k0];
  unsigned a0 = f2bf(s[0]) | ((unsigned)f2bf(s[1]) << 16);
  unsigned a1 = f2bf(s[2]) | ((unsigned)f2bf(s[3]) << 16);
  unsigned a2 = f2bf(s[4]) | ((unsigned)f2bf(s[5]) << 16);
  unsigned a3 = f2bf(s[6]) | ((unsigned)f2bf(s[7]) << 16);
  dst[tid] = (uint4){a0, a1, a2, a3};
}

// h0[b][n] = sum_o init[b][o] * Whi[n][o]; also bf16 copy for step-0 staging
__global__ void h0_kernel(const float* __restrict__ init, const float* __restrict__ Whi,
                          float* __restrict__ h0, unsigned short* __restrict__ hb0){
  int b = blockIdx.x, n = threadIdx.x;  // 256 x 512
  __shared__ float ic[512];
  ic[n] = init[b * 512 + n];
  __syncthreads();
  const float4* wr = (const float4*)&Whi[n * 512];
  float s = 0.f;
  #pragma unroll 8
  for (int o = 0; o < 128; o++){
    float4 w = wr[o];
    s += w.x * ic[4*o] + w.y * ic[4*o+1] + w.z * ic[4*o+2] + w.w * ic[4*o+3];
  }
  h0[b * 512 + n] = s;
  hb0[b * 512 + n] = f2bf(s);
}

// Fused kernel: WGs 0..15 = r10 "fortress" rnn (unchanged internals) +
// per-64-step progress publish (r2-proven release protocol).
// WGs 16..1039 = out_gemm tile consumers: spin on progress (r3-proven agent
// poll), stage hidden via agent-scope 8B atomic loads (LLC-coherent).
__global__ __launch_bounds__(512, 1)
void rnn_gemm(const float* __restrict__ inputs, const float* __restrict__ W_in,
              const float* __restrict__ b_in, const float* __restrict__ b_rec,
              const uint4* __restrict__ wfrag, const uint4* __restrict__ wofrag,
              const float* __restrict__ h0, const unsigned short* __restrict__ hb0,
              int* __restrict__ progress, float* __restrict__ hidden,
              float* __restrict__ outp){
  __shared__ char smem[147456];
  const int bid = blockIdx.x;
  const int tid = threadIdx.x, w = tid >> 6, lane = tid & 63;
  const int col = lane & 15, quad = lane >> 4;

  if (bid < 16){
    // ================= RNN role (r10 verbatim + publish) =================
    const int m = bid;
    const int g16 = m << 4;
    const int nbase = w << 6;
    const int swc = (col & 7) << 3;
    unsigned short* hbuf = (unsigned short*)smem;          // 16 KB
    uint4* wlds = (uint4*)(smem + 16384);                  // 128 KB: [w][16][64]

    UQ u[32];
    #pragma unroll
    for (int kt = 0; kt < 8; kt++)
      #pragma unroll
      for (int nt = 0; nt < 4; nt++){
        const uint4* src = &wfrag[(((w << 2) + nt) * 16 + kt) * 64 + lane];
        asm volatile("global_load_dwordx4 %0, %1, off"
                     : "=v"(u[kt * 4 + nt].p) : "v"(src) : "memory");
      }
    asm volatile("s_waitcnt vmcnt(0)" ::: "memory");
    #pragma unroll
    for (int j = 0; j < 32; j++)
      asm volatile("" : "+v"(u[j].d[0]), "+v"(u[j].d[1]));

    #pragma unroll
    for (int kt = 8; kt < 12; kt++)
      #pragma unroll
      for (int nt = 0; nt < 4; nt++)
        wlds[(w * 16 + (kt - 8) * 4 + nt) * 64 + lane] =
            wfrag[(((w << 2) + nt) * 16 + kt) * 64 + lane];

    UQ uaug[4];
    #pragma unroll
    for (int nt = 0; nt < 4; nt++){
      uaug[nt].d[0] = 0; uaug[nt].d[1] = 0;
      if (quad == 0){
        int n = nbase + nt * 16 + col;
        uaug[nt].b[0] = (__bf16)W_in[2 * n];
        uaug[nt].b[1] = (__bf16)W_in[2 * n + 1];
        uaug[nt].b[2] = (__bf16)(b_in[n] + b_rec[n]);
      }
    }

    float h[16];
    #pragma unroll
    for (int nt = 0; nt < 4; nt++){
      float4 h4 = *(const float4*)&h0[(g16 + col) * 512 + nbase + nt * 16 + (quad << 2)];
      h[nt*4+0] = h4.x; h[nt*4+1] = h4.y; h[nt*4+2] = h4.z; h[nt*4+3] = h4.w;
    }

    {
      int b = tid >> 5, n0 = (tid & 31) << 4;
      const uint4* s4 = (const uint4*)&hb0[(g16 + b) * 512 + n0];
      uint4 v0 = s4[0], v1 = s4[1];
      int sw = (b & 7) << 3;
      *(uint4*)&hbuf[(b << 9) + (n0 ^ sw)]       = v0;
      *(uint4*)&hbuf[(b << 9) + ((n0 + 8) ^ sw)] = v1;
    }
    __syncthreads();

    unsigned long long wsp = (unsigned long long)wfrag;
    const float2* xsrc = (const float2*)&inputs[((size_t)(g16 + col)) << 10];

#define ISSUE(b1) { const int kt_ = 12 + (b1);                                    \
    _Pragma("unroll")                                                             \
    for (int nt_ = 0; nt_ < 4; nt_++)                                             \
      sv[(b1)*4 + nt_].q = ws[(((w << 2) + nt_) * 16 + kt_) * 64 + lane]; }

#define HREAD(kt_) *(const uint4*)&hbuf[(col << 9) + ((((kt_) << 5) + (quad << 3)) ^ swc)]

    for (int t = 0; t < 512; t++){
      asm volatile("" : "+s"(wsp));
      const uint4* ws = (const uint4*)wsp;

      UQ baug; baug.d[0] = 0; baug.d[1] = 0;
      float2 xv = xsrc[t];
      if (quad == 0){
        baug.b[0] = (__bf16)xv.x; baug.b[1] = (__bf16)xv.y; baug.b[2] = (__bf16)1.0f;
      }

      f32x4 acc[4];
      #pragma unroll
      for (int nt = 0; nt < 4; nt++)
        acc[nt] = __builtin_amdgcn_mfma_f32_16x16x32_bf16(uaug[nt].v, baug.v,
                                                          (f32x4){0.f,0.f,0.f,0.f}, 0, 0, 0);

      UQ sv[16];
      ISSUE(0);
      UQ bh[16];
      #pragma unroll
      for (int kt = 0; kt < 16; kt++)
        bh[kt].q = HREAD(kt);

      #pragma unroll
      for (int kt = 0; kt < 8; kt++){
        #pragma unroll
        for (int nt = 0; nt < 4; nt++)
          acc[nt] = __builtin_amdgcn_mfma_f32_16x16x32_bf16(u[kt*4+nt].v, bh[kt].v, acc[nt], 0, 0, 0);
        if (kt == 0) ISSUE(1);
        if (kt == 2) ISSUE(2);
        if (kt == 4) ISSUE(3);
      }
      #pragma unroll
      for (int kt = 8; kt < 12; kt++){
        #pragma unroll
        for (int nt = 0; nt < 4; nt++){
          UQ a; a.q = wlds[(w * 16 + (kt - 8) * 4 + nt) * 64 + lane];
          acc[nt] = __builtin_amdgcn_mfma_f32_16x16x32_bf16(a.v, bh[kt].v, acc[nt], 0, 0, 0);
        }
      }
      #pragma unroll
      for (int kt = 12; kt < 16; kt++){
        #pragma unroll
        for (int nt = 0; nt < 4; nt++)
          acc[nt] = __builtin_amdgcn_mfma_f32_16x16x32_bf16(sv[(kt-12)*4+nt].v, bh[kt].v, acc[nt], 0, 0, 0);
      }

      __syncthreads();   // barrier A

      #pragma unroll
      for (int nt = 0; nt < 4; nt++){
        UQ hw; hw.d[0] = 0; hw.d[1] = 0;
        #pragma unroll
        for (int r = 0; r < 4; r++){
          float z  = acc[nt][r];
          float e  = __expf(2.0f * z);
          float rc = __builtin_amdgcn_rcpf(e + 1.0f);
          float hn = fmaf(0.9f, h[nt*4+r], 0.1f) - 0.2f * rc;
          h[nt*4+r] = hn;
          hw.b[r] = (__bf16)hn;
        }
        *(unsigned long long*)&hbuf[(col << 9) + ((nbase + (nt << 4) + (quad << 2)) ^ swc)] = hw.d[0];
        *(float4*)&hidden[((size_t)(g16 + col) * 512 + t) * 512 + nbase + (nt << 4) + (quad << 2)] =
            (float4){h[nt*4+0], h[nt*4+1], h[nt*4+2], h[nt*4+3]};
      }
      __syncthreads();   // barrier B

      if (((t + 1) & 63) == 0){
        asm volatile("s_waitcnt vmcnt(0)" ::: "memory");  // hidden stores at L2
        __syncthreads();                                  // all waves drained
        if (tid == 0){
          __builtin_amdgcn_fence(__ATOMIC_RELEASE, "agent");   // L2 -> LLC
          __hip_atomic_store(&progress[m], t + 1, __ATOMIC_RELAXED, __HIP_MEMORY_SCOPE_AGENT);
        }
      }
    }
#undef ISSUE
#undef HREAD
  } else {
    // ================= GEMM role (r10 out_gemm + spin + atomic stage) ======
    const int gid = bid - 16;
    const int m0  = gid << 7;                 // row base in hidden (b*512+t)
    const int grp = gid >> 6;                 // rnn group producing this batch
    const int thr = (m0 & 511) + 128;         // steps needed
    const int ms  = w >> 1;
    const int nh  = w & 1;
    unsigned short* albf = (unsigned short*)smem;   // 8 KB
    uint4* wq = (uint4*)(smem + 8192);              // 32 KB: [32][64]

    if (tid == 0)
      while (__hip_atomic_load(&progress[grp], __ATOMIC_RELAXED,
                               __HIP_MEMORY_SCOPE_AGENT) < thr) {}
    __syncthreads();

    f32x4 acc[2][16];
    #pragma unroll
    for (int mt = 0; mt < 2; mt++)
      #pragma unroll
      for (int nt = 0; nt < 16; nt++) acc[mt][nt] = (f32x4){0.f, 0.f, 0.f, 0.f};

    for (int kt = 0; kt < 16; kt++){
      #pragma unroll
      for (int i = 0; i < 2; i++){
        int r  = (tid >> 3) + (i << 6);
        int c4 = (tid & 7) << 2;
        const unsigned long long* hp =
            (const unsigned long long*)&hidden[(size_t)(m0 + r) * 512 + (kt << 5) + c4];
        unsigned long long d0 = __hip_atomic_load(hp,     __ATOMIC_RELAXED, __HIP_MEMORY_SCOPE_AGENT);
        unsigned long long d1 = __hip_atomic_load(hp + 1, __ATOMIC_RELAXED, __HIP_MEMORY_SCOPE_AGENT);
        union { unsigned long long d[2]; float f[4]; } cv; cv.d[0] = d0; cv.d[1] = d1;
        unsigned lo = f2bf(cv.f[0]) | ((unsigned)f2bf(cv.f[1]) << 16);
        unsigned hi = f2bf(cv.f[2]) | ((unsigned)f2bf(cv.f[3]) << 16);
        int byteoff = (r << 6) + ((c4 << 1) ^ (((r >> 1) & 3) << 4));
        *(uint2*)(smem + byteoff) = (uint2){lo, hi};
      }
      #pragma unroll
      for (int j = 0; j < 4; j++){
        int idx = (j << 9) + tid;            // 0..2047
        wq[(idx >> 6) * 64 + (idx & 63)] = wofrag[(((idx >> 6) << 4) + kt) * 64 + (idx & 63)];
      }
      __syncthreads();

      bf16x8 af[2];
      #pragma unroll
      for (int mt = 0; mt < 2; mt++){
        int rl = (ms << 5) + (mt << 4) + col;
        int byteoff = (rl << 6) + ((quad << 4) ^ (((rl >> 1) & 3) << 4));
        af[mt] = *(const bf16x8*)((const char*)albf + byteoff);
      }

      #pragma unroll
      for (int nt = 0; nt < 16; nt++){
        UQ uu; uu.q = wq[((nh << 4) + nt) * 64 + lane];
        acc[0][nt] = __builtin_amdgcn_mfma_f32_16x16x32_bf16(af[0], uu.v, acc[0][nt], 0, 0, 0);
        acc[1][nt] = __builtin_amdgcn_mfma_f32_16x16x32_bf16(af[1], uu.v, acc[1][nt], 0, 0, 0);
      }
      __syncthreads();
    }

    #pragma unroll
    for (int mt = 0; mt < 2; mt++)
      #pragma unroll
      for (int nt = 0; nt < 16; nt++)
        #pragma unroll
        for (int r = 0; r < 4; r++)
          outp[(size_t)(m0 + (ms << 5) + (mt << 4) + (quad << 2) + r) * 512
               + (nh << 8) + (nt << 4) + col] = acc[mt][nt][r];
  }
}

extern "C" void kernel_launch(void* const* d_in, const int* in_sizes, int n_in,
                              void* d_out, int out_size, void* d_ws, size_t ws_size,
                              hipStream_t stream){
  const float* inputs  = (const float*)d_in[0];  // (256,512,2)
  const float* initc   = (const float*)d_in[1];  // (256,512)
  const float* W_in    = (const float*)d_in[2];  // (512,2)
  const float* b_in    = (const float*)d_in[3];  // (512)
  const float* W_rec   = (const float*)d_in[4];  // (512,512)
  const float* b_rec   = (const float*)d_in[5];  // (512)
  const float* W_out   = (const float*)d_in[6];  // (512,512)
  const float* W_hi    = (const float*)d_in[7];  // (512,512)

  float* hidden  = (float*)d_out;                 // 256*512*512
  float* outputs = hidden + (size_t)67108864;     // second half

  char* ws = (char*)d_ws;
  uint4*          wrec_f  = (uint4*)ws;                           // 512 KB
  uint4*          wout_f  = (uint4*)(ws + (512 << 10));           // 512 KB
  float*          h0      = (float*)(ws + (1024 << 10));          // 512 KB
  unsigned short* hb0     = (unsigned short*)(ws + (1536 << 10)); // 256 KB
  int*            progress= (int*)(ws + (1792 << 10));            // 64 B

  zero_flags<<<1, 64, 0, stream>>>(progress);
  pack_kernel<<<64, 512, 0, stream>>>(W_rec, wrec_f);
  pack_kernel<<<64, 512, 0, stream>>>(W_out, wout_f);
  h0_kernel<<<256, 512, 0, stream>>>(initc, W_hi, h0, hb0);
  rnn_gemm<<<1040, 512, 0, stream>>>(inputs, W_in, b_in, b_rec, wrec_f, wout_f,
                                     h0, hb0, progress, hidden, outputs);
}

// Round 16
// 1718.532 us; speedup vs baseline: 1.4709x; 1.0497x over previous
//
#include <hip/hip_runtime.h>

typedef __bf16 bf16x8 __attribute__((ext_vector_type(8)));
typedef float f32x4 __attribute__((ext_vector_type(4)));
typedef unsigned int u32x4 __attribute__((ext_vector_type(4)));

union UQ { uint4 q; u32x4 p; bf16x8 v; __bf16 b[8]; unsigned long long d[2]; };

__device__ __forceinline__ unsigned short f2bf(float x){
  union { float f; unsigned u; } c; c.f = x;
  return (unsigned short)((c.u + 0x7fffu + ((c.u >> 16) & 1u)) >> 16);
}

__global__ void zero_flags(int* __restrict__ p){
  p[threadIdx.x] = 0;
}

// Pack W (512x512 f32 row-major) into canonical MFMA fragment stream:
// dst[(ntile*16 + kt)*64 + lane] = 8 bf16 of W[ntile*16 + (lane&15)][kt*32 + (lane>>4)*8 + j]
__global__ void pack_kernel(const float* __restrict__ W, uint4* __restrict__ dst){
  int tid  = blockIdx.x * 512 + threadIdx.x;   // 0..32767
  int lane = tid & 63;
  int kt   = (tid >> 6) & 15;
  int ntl  = tid >> 10;
  int row  = ntl * 16 + (lane & 15);
  int k0   = kt * 32 + ((lane >> 4) << 3);
  const float* s = &W[row * 512 + k0];
  unsigned a0 = f2bf(s[0]) | ((unsigned)f2bf(s[1]) << 16);
  unsigned a1 = f2bf(s[2]) | ((unsigned)f2bf(s[3]) << 16);
  unsigned a2 = f2bf(s[4]) | ((unsigned)f2bf(s[5]) << 16);
  unsigned a3 = f2bf(s[6]) | ((unsigned)f2bf(s[7]) << 16);
  dst[tid] = (uint4){a0, a1, a2, a3};
}

// h0[b][n] = sum_o init[b][o] * Whi[n][o]; also bf16 copy for step-0 staging
__global__ void h0_kernel(const float* __restrict__ init, const float* __restrict__ Whi,
                          float* __restrict__ h0, unsigned short* __restrict__ hb0){
  int b = blockIdx.x, n = threadIdx.x;  // 256 x 512
  __shared__ float ic[512];
  ic[n] = init[b * 512 + n];
  __syncthreads();
  const float4* wr = (const float4*)&Whi[n * 512];
  float s = 0.f;
  #pragma unroll 8
  for (int o = 0; o < 128; o++){
    float4 w = wr[o];
    s += w.x * ic[4*o] + w.y * ic[4*o+1] + w.z * ic[4*o+2] + w.w * ic[4*o+3];
  }
  h0[b * 512 + n] = s;
  hb0[b * 512 + n] = f2bf(s);
}

// Fused kernel: WGs 0..15 = r10 "fortress" rnn + per-64-step progress publish
// (r15-proven). WGs 16..2063 = out_gemm 64-row-tile consumers, t-chunk-major
// order (dispatch order == readiness order), upfront pipelined atomic staging.
__global__ __launch_bounds__(512, 1)
void rnn_gemm(const float* __restrict__ inputs, const float* __restrict__ W_in,
              const float* __restrict__ b_in, const float* __restrict__ b_rec,
              const uint4* __restrict__ wfrag, const uint4* __restrict__ wofrag,
              const float* __restrict__ h0, const unsigned short* __restrict__ hb0,
              int* __restrict__ progress, float* __restrict__ hidden,
              float* __restrict__ outp){
  __shared__ char smem[147456];
  const int bid = blockIdx.x;
  const int tid = threadIdx.x, w = tid >> 6, lane = tid & 63;
  const int col = lane & 15, quad = lane >> 4;

  if (bid < 16){
    // ================= RNN role (r15 verbatim) =================
    const int m = bid;
    const int g16 = m << 4;
    const int nbase = w << 6;
    const int swc = (col & 7) << 3;
    unsigned short* hbuf = (unsigned short*)smem;          // 16 KB
    uint4* wlds = (uint4*)(smem + 16384);                  // 128 KB

    UQ u[32];
    #pragma unroll
    for (int kt = 0; kt < 8; kt++)
      #pragma unroll
      for (int nt = 0; nt < 4; nt++){
        const uint4* src = &wfrag[(((w << 2) + nt) * 16 + kt) * 64 + lane];
        asm volatile("global_load_dwordx4 %0, %1, off"
                     : "=v"(u[kt * 4 + nt].p) : "v"(src) : "memory");
      }
    asm volatile("s_waitcnt vmcnt(0)" ::: "memory");
    #pragma unroll
    for (int j = 0; j < 32; j++)
      asm volatile("" : "+v"(u[j].d[0]), "+v"(u[j].d[1]));

    #pragma unroll
    for (int kt = 8; kt < 12; kt++)
      #pragma unroll
      for (int nt = 0; nt < 4; nt++)
        wlds[(w * 16 + (kt - 8) * 4 + nt) * 64 + lane] =
            wfrag[(((w << 2) + nt) * 16 + kt) * 64 + lane];

    UQ uaug[4];
    #pragma unroll
    for (int nt = 0; nt < 4; nt++){
      uaug[nt].d[0] = 0; uaug[nt].d[1] = 0;
      if (quad == 0){
        int n = nbase + nt * 16 + col;
        uaug[nt].b[0] = (__bf16)W_in[2 * n];
        uaug[nt].b[1] = (__bf16)W_in[2 * n + 1];
        uaug[nt].b[2] = (__bf16)(b_in[n] + b_rec[n]);
      }
    }

    float h[16];
    #pragma unroll
    for (int nt = 0; nt < 4; nt++){
      float4 h4 = *(const float4*)&h0[(g16 + col) * 512 + nbase + nt * 16 + (quad << 2)];
      h[nt*4+0] = h4.x; h[nt*4+1] = h4.y; h[nt*4+2] = h4.z; h[nt*4+3] = h4.w;
    }

    {
      int b = tid >> 5, n0 = (tid & 31) << 4;
      const uint4* s4 = (const uint4*)&hb0[(g16 + b) * 512 + n0];
      uint4 v0 = s4[0], v1 = s4[1];
      int sw = (b & 7) << 3;
      *(uint4*)&hbuf[(b << 9) + (n0 ^ sw)]       = v0;
      *(uint4*)&hbuf[(b << 9) + ((n0 + 8) ^ sw)] = v1;
    }
    __syncthreads();

    unsigned long long wsp = (unsigned long long)wfrag;
    const float2* xsrc = (const float2*)&inputs[((size_t)(g16 + col)) << 10];

#define ISSUE(b1) { const int kt_ = 12 + (b1);                                    \
    _Pragma("unroll")                                                             \
    for (int nt_ = 0; nt_ < 4; nt_++)                                             \
      sv[(b1)*4 + nt_].q = ws[(((w << 2) + nt_) * 16 + kt_) * 64 + lane]; }

#define HREAD(kt_) *(const uint4*)&hbuf[(col << 9) + ((((kt_) << 5) + (quad << 3)) ^ swc)]

    for (int t = 0; t < 512; t++){
      asm volatile("" : "+s"(wsp));
      const uint4* ws = (const uint4*)wsp;

      UQ baug; baug.d[0] = 0; baug.d[1] = 0;
      float2 xv = xsrc[t];
      if (quad == 0){
        baug.b[0] = (__bf16)xv.x; baug.b[1] = (__bf16)xv.y; baug.b[2] = (__bf16)1.0f;
      }

      f32x4 acc[4];
      #pragma unroll
      for (int nt = 0; nt < 4; nt++)
        acc[nt] = __builtin_amdgcn_mfma_f32_16x16x32_bf16(uaug[nt].v, baug.v,
                                                          (f32x4){0.f,0.f,0.f,0.f}, 0, 0, 0);

      UQ sv[16];
      ISSUE(0);
      UQ bh[16];
      #pragma unroll
      for (int kt = 0; kt < 16; kt++)
        bh[kt].q = HREAD(kt);

      #pragma unroll
      for (int kt = 0; kt < 8; kt++){
        #pragma unroll
        for (int nt = 0; nt < 4; nt++)
          acc[nt] = __builtin_amdgcn_mfma_f32_16x16x32_bf16(u[kt*4+nt].v, bh[kt].v, acc[nt], 0, 0, 0);
        if (kt == 0) ISSUE(1);
        if (kt == 2) ISSUE(2);
        if (kt == 4) ISSUE(3);
      }
      #pragma unroll
      for (int kt = 8; kt < 12; kt++){
        #pragma unroll
        for (int nt = 0; nt < 4; nt++){
          UQ a; a.q = wlds[(w * 16 + (kt - 8) * 4 + nt) * 64 + lane];
          acc[nt] = __builtin_amdgcn_mfma_f32_16x16x32_bf16(a.v, bh[kt].v, acc[nt], 0, 0, 0);
        }
      }
      #pragma unroll
      for (int kt = 12; kt < 16; kt++){
        #pragma unroll
        for (int nt = 0; nt < 4; nt++)
          acc[nt] = __builtin_amdgcn_mfma_f32_16x16x32_bf16(sv[(kt-12)*4+nt].v, bh[kt].v, acc[nt], 0, 0, 0);
      }

      __syncthreads();   // barrier A

      #pragma unroll
      for (int nt = 0; nt < 4; nt++){
        UQ hw; hw.d[0] = 0; hw.d[1] = 0;
        #pragma unroll
        for (int r = 0; r < 4; r++){
          float z  = acc[nt][r];
          float e  = __expf(2.0f * z);
          float rc = __builtin_amdgcn_rcpf(e + 1.0f);
          float hn = fmaf(0.9f, h[nt*4+r], 0.1f) - 0.2f * rc;
          h[nt*4+r] = hn;
          hw.b[r] = (__bf16)hn;
        }
        *(unsigned long long*)&hbuf[(col << 9) + ((nbase + (nt << 4) + (quad << 2)) ^ swc)] = hw.d[0];
        *(float4*)&hidden[((size_t)(g16 + col) * 512 + t) * 512 + nbase + (nt << 4) + (quad << 2)] =
            (float4){h[nt*4+0], h[nt*4+1], h[nt*4+2], h[nt*4+3]};
      }
      __syncthreads();   // barrier B

      if (((t + 1) & 63) == 0){
        asm volatile("s_waitcnt vmcnt(0)" ::: "memory");
        __syncthreads();
        if (tid == 0){
          __builtin_amdgcn_fence(__ATOMIC_RELEASE, "agent");
          __hip_atomic_store(&progress[m], t + 1, __ATOMIC_RELAXED, __HIP_MEMORY_SCOPE_AGENT);
        }
      }
    }
#undef ISSUE
#undef HREAD
  } else {
    // ========== GEMM role: 64-row tiles, t-chunk-major, upfront staging ======
    const int gid = bid - 16;                 // 0..2047
    const int tchunk = gid >> 8;              // 0..7  (dispatch order == time)
    const int b   = gid & 255;                // batch
    const int t0  = tchunk << 6;
    const int m0  = (b << 9) + t0;            // row base (64 rows)
    const int grp = b >> 4;
    const int ms  = w >> 1;                   // 0..3: 16-row slice
    const int nh  = w & 1;                    // 0..1: 256-col half
    unsigned short* albf = (unsigned short*)smem;      // 64 KB A-tile (64x512 bf16)
    uint4* wq = (uint4*)(smem + 65536);                // 32 KB W-frags per kt

    if (tid == 0)
      while (__hip_atomic_load(&progress[grp], __ATOMIC_RELAXED,
                               __HIP_MEMORY_SCOPE_AGENT) < t0 + 64) {}
    __syncthreads();

    // ---- stage full 64x512 A-tile: 32 pipelined atomic ULL loads per thread
    {
      const int r  = tid >> 3;                // 0..63
      const int c0 = (tid & 7) << 6;          // 0..448
      const unsigned long long* hp =
          (const unsigned long long*)&hidden[(size_t)(m0 + r) * 512 + c0];
      unsigned long long dv[32];
      #pragma unroll
      for (int j = 0; j < 32; j++)
        dv[j] = __hip_atomic_load(hp + j, __ATOMIC_RELAXED, __HIP_MEMORY_SCOPE_AGENT);
      const int sw = (r & 7) << 4;            // byte swizzle
      #pragma unroll
      for (int g = 0; g < 8; g++){            // 8 cols per group -> uint4
        union { unsigned long long d[4]; float f[8]; } cv;
        cv.d[0] = dv[g*4]; cv.d[1] = dv[g*4+1]; cv.d[2] = dv[g*4+2]; cv.d[3] = dv[g*4+3];
        uint4 o;
        o.x = f2bf(cv.f[0]) | ((unsigned)f2bf(cv.f[1]) << 16);
        o.y = f2bf(cv.f[2]) | ((unsigned)f2bf(cv.f[3]) << 16);
        o.z = f2bf(cv.f[4]) | ((unsigned)f2bf(cv.f[5]) << 16);
        o.w = f2bf(cv.f[6]) | ((unsigned)f2bf(cv.f[7]) << 16);
        int byteoff = (r << 10) + ((((c0 + (g << 3)) << 1)) ^ sw);
        *(uint4*)((char*)albf + byteoff) = o;
      }
    }
    __syncthreads();

    f32x4 acc[16];
    #pragma unroll
    for (int nt = 0; nt < 16; nt++) acc[nt] = (f32x4){0.f, 0.f, 0.f, 0.f};

    for (int kt = 0; kt < 16; kt++){
      // stage W-frags for this kt: 32 frags x 64 lanes, 4 per thread
      #pragma unroll
      for (int j = 0; j < 4; j++){
        int idx = (j << 9) + tid;             // 0..2047
        wq[(idx >> 6) * 64 + (idx & 63)] = wofrag[(((idx >> 6) << 4) + kt) * 64 + (idx & 63)];
      }
      __syncthreads();

      bf16x8 af;
      {
        int rl = (ms << 4) + col;
        int byteoff = (rl << 10) + (((kt << 6) + (quad << 4)) ^ ((rl & 7) << 4));
        af = *(const bf16x8*)((const char*)albf + byteoff);
      }

      #pragma unroll
      for (int nt = 0; nt < 16; nt++){
        UQ uu; uu.q = wq[((nh << 4) + nt) * 64 + lane];
        acc[nt] = __builtin_amdgcn_mfma_f32_16x16x32_bf16(af, uu.v, acc[nt], 0, 0, 0);
      }
      __syncthreads();
    }

    #pragma unroll
    for (int nt = 0; nt < 16; nt++)
      #pragma unroll
      for (int r = 0; r < 4; r++)
        outp[(size_t)(m0 + (ms << 4) + (quad << 2) + r) * 512
             + (nh << 8) + (nt << 4) + col] = acc[nt][r];
  }
}

extern "C" void kernel_launch(void* const* d_in, const int* in_sizes, int n_in,
                              void* d_out, int out_size, void* d_ws, size_t ws_size,
                              hipStream_t stream){
  const float* inputs  = (const float*)d_in[0];  // (256,512,2)
  const float* initc   = (const float*)d_in[1];  // (256,512)
  const float* W_in    = (const float*)d_in[2];  // (512,2)
  const float* b_in    = (const float*)d_in[3];  // (512)
  const float* W_rec   = (const float*)d_in[4];  // (512,512)
  const float* b_rec   = (const float*)d_in[5];  // (512)
  const float* W_out   = (const float*)d_in[6];  // (512,512)
  const float* W_hi    = (const float*)d_in[7];  // (512,512)

  float* hidden  = (float*)d_out;                 // 256*512*512
  float* outputs = hidden + (size_t)67108864;     // second half

  char* ws = (char*)d_ws;
  uint4*          wrec_f  = (uint4*)ws;                           // 512 KB
  uint4*          wout_f  = (uint4*)(ws + (512 << 10));           // 512 KB
  float*          h0      = (float*)(ws + (1024 << 10));          // 512 KB
  unsigned short* hb0     = (unsigned short*)(ws + (1536 << 10)); // 256 KB
  int*            progress= (int*)(ws + (1792 << 10));            // 64 B

  zero_flags<<<1, 64, 0, stream>>>(progress);
  pack_kernel<<<64, 512, 0, stream>>>(W_rec, wrec_f);
  pack_kernel<<<64, 512, 0, stream>>>(W_out, wout_f);
  h0_kernel<<<256, 512, 0, stream>>>(initc, W_hi, h0, hb0);
  rnn_gemm<<<2064, 512, 0, stream>>>(inputs, W_in, b_in, b_rec, wrec_f, wout_f,
                                     h0, hb0, progress, hidden, outputs);
}